// Round 12
// baseline (197.395 us; speedup 1.0000x reference)
//
#include <hip/hip_runtime.h>

// MultiHeadAttention: B=2, T=2048, C=1024, H=16, Dh=64, causal, scale = C^-0.5 = 1/32.
// FP32 I/O (proven R5). bf16 MFMA pipeline, fp32 accumulation.
//
//   1. ingest: R18 LDS-tiled transposes (proven).
//   2. qkv:    128x128 GEMM, R17 2-phase dbuf. Q scale = 1/32*log2e (R20).
//   3. attn_part: R22 LDS-shared K/V (proven: attn 79->~46us) + R23 K/V
//      DOUBLE-BUFFER. R22 issued stageKV(next) immediately before the
//      loop-top barrier that drains it -> full staging latency exposed per
//      iter. Now R17's proven stage-early/drain-late: stage t+1 into buf^1
//      at iter top, compute t from buf, ONE barrier per tile (was two).
//      LDS 32->48KB (3 blocks/CU, was 4) — trades 1 block of TLP for
//      in-block latency hiding + halved barrier count.
//      R24: identical resubmit (R23 bench was an infra failure, no data).
//   4. attn_merge: R13 <=4-partial merge, weights = raw l (exact).
//   5. proj:   R17 2-phase GEMM. bias + fp32 out.
//
// ws layout (16M shorts = 32 MB):
//   wpT[0,1M) qb[1M,5.24M) wt[9.44M,12.58M) xb[12.58M,16.77M)
//   after qkv: po[5.24M,15.73M) = 40*32 x 128 x 64 bf16; pl[15.73M,+163840f)
//   attnb[1M,5.24M) overlays dead qb. K/V^T in d_out until proj.
//
// MFMA fragment layouts (HW-verified R6/R7):
//   A:   lane holds A[m=lane&15][k=quad*8+j], j=0..7   (quad = lane>>4)
//   B:   lane holds B[k=quad*8+j][n=lane&15]
//   C/D: lane holds D[m=quad*4+r][n=lane&15], r=0..3

typedef unsigned short u16;
typedef unsigned int u32;

using bf16x8 = __attribute__((ext_vector_type(8))) short;
using bf16x4 = __attribute__((ext_vector_type(4))) short;
using f32x4  = __attribute__((ext_vector_type(4))) float;

#define T_SEQ 2048
#define C_DIM 1024
#define H_NUM 16
#define D_HEAD 64
#define NCHUNK 40

static __device__ inline f32x4 mfma16(bf16x8 a, bf16x8 b, f32x4 c) {
  return __builtin_amdgcn_mfma_f32_16x16x32_bf16(a, b, c, 0, 0, 0);
}

static __device__ inline short f2bf(float f) {
  union { float f; u32 u; } v; v.f = f;
  u32 u = v.u;
  return (short)((u + 0x7FFFu + ((u >> 16) & 1u)) >> 16);
}

static __device__ inline float bf2f(short s) {
  union { u32 u; float f; } v; v.u = ((u32)(u16)s) << 16;
  return v.f;
}

// bare v_exp_f32: computes 2^x
static __device__ inline float exp2_hw(float x) {
  return __builtin_amdgcn_exp2f(x);
}

// pack 2 f32 -> 1 u32 of 2 bf16 (lo=a, hi=b), single HW instr
static __device__ inline u32 cvtpk_bf16(float a, float b) {
  u32 r;
  asm("v_cvt_pk_bf16_f32 %0, %1, %2" : "=v"(r) : "v"(a), "v"(b));
  return r;
}

// async global->LDS, 16B per lane; LDS dst = wave-uniform base + lane*16
static __device__ inline void gload_lds16(const short* g, short* l) {
  __builtin_amdgcn_global_load_lds(
      (const __attribute__((address_space(1))) unsigned int*)g,
      (__attribute__((address_space(3))) unsigned int*)l,
      16, 0, 0);
}

// ---------------------------------------------------------------------------
// Kernel 1: ingest, R18 tiled. grid 5120 x 256.
__global__ __launch_bounds__(256) void ingest_kernel(
    const float* __restrict__ x, const float* __restrict__ wq,
    const float* __restrict__ wk, const float* __restrict__ wv,
    const float* __restrict__ wproj,
    short* __restrict__ xb, short* __restrict__ wt, short* __restrict__ wpT) {
  const int bid = blockIdx.x, t = threadIdx.x;
  if (bid < 4096) {
    size_t i4 = ((size_t)bid * 256 + t) * 4;
    const float4 v = *(const float4*)(x + i4);
    bf16x4 o4;
    o4[0] = f2bf(v.x); o4[1] = f2bf(v.y); o4[2] = f2bf(v.z); o4[3] = f2bf(v.w);
    *(bf16x4*)(xb + i4) = o4;
    return;
  }
  __shared__ short lt[64][72];
  const int rl = t >> 2, q16 = (t & 3) * 16;
  if (bid < 4864) {
    const int wb = bid - 4096;
    const int h3 = wb >> 4, c0 = (wb & 15) * 64;
    const float* w = (h3 < 16) ? wq : (h3 < 32) ? wk : wv;
    const int h = h3 & 15;
    const float* rp = w + (size_t)h * 65536 + (size_t)(c0 + rl) * 64 + q16;
#pragma unroll
    for (int j = 0; j < 16; j++) lt[rl][q16 + j] = f2bf(rp[j]);
    __syncthreads();
    short* op = wt + (size_t)h3 * 65536 + (size_t)rl * 1024 + c0 + q16;
#pragma unroll
    for (int j = 0; j < 16; j++) op[j] = lt[q16 + j][rl];
  } else {
    const int wc = bid - 4864;
    const int k0 = (wc >> 4) * 64, n0 = (wc & 15) * 64;
    const float* rp = wproj + (size_t)(k0 + rl) * 1024 + n0 + q16;
#pragma unroll
    for (int j = 0; j < 16; j++) lt[rl][q16 + j] = f2bf(rp[j]);
    __syncthreads();
    short* op = wpT + (size_t)(n0 + rl) * 1024 + k0 + q16;
#pragma unroll
    for (int j = 0; j < 16; j++) op[j] = lt[q16 + j][rl];
  }
}

// ---------------------------------------------------------------------------
// Kernel 2: QKV GEMM, R17 2-phase double-buffered. grid (32, 24), 256 thr.
__global__ __launch_bounds__(256) void qkv_kernel(
    const short* __restrict__ x, const short* __restrict__ wt,
    short* __restrict__ qo, short* __restrict__ ko, short* __restrict__ vto) {
  const int m0 = blockIdx.x * 128;
  const int n0 = blockIdx.y * 128;
  const int tid = threadIdx.x, w = tid >> 6, lane = tid & 63;
  const int l15 = lane & 15, quad = lane >> 4;
  const int wm = w >> 1, wn = w & 1;

  __shared__ __align__(16) short As[2][128 * 32];
  __shared__ __align__(16) short Bs[2][128 * 32];

  const int srow = w * 32 + (lane >> 2);
  const int skof = (lane & 3) * 8;
  const short* ga0 = x  + (size_t)(m0 + srow) * 1024 + skof;
  const short* ga1 = ga0 + 16 * 1024;
  const short* gb0 = wt + (size_t)(n0 + srow) * 1024 + skof;
  const short* gb1 = gb0 + 16 * 1024;
  const int lof0 = (w * 32) * 32;
  const int lof1 = (w * 32 + 16) * 32;

  f32x4 acc[4][4];
#pragma unroll
  for (int i = 0; i < 4; i++)
#pragma unroll
    for (int j = 0; j < 4; j++) acc[i][j] = f32x4{0, 0, 0, 0};

  const bool isv = (n0 >= 2048);   // V column-blocks: operand-swap mode

  auto stage = [&](int bi, int kt) {
    const int k0 = kt * 32;
    gload_lds16(ga0 + k0, &As[bi][lof0]);
    gload_lds16(ga1 + k0, &As[bi][lof1]);
    gload_lds16(gb0 + k0, &Bs[bi][lof0]);
    gload_lds16(gb1 + k0, &Bs[bi][lof1]);
  };
  auto compute = [&](int bi) {
    const short* ard = &As[bi][(wm * 64 + l15) * 32 + quad * 8];
    const short* brd = &Bs[bi][(wn * 64 + l15) * 32 + quad * 8];
    bf16x8 af[4], bfr[4];
#pragma unroll
    for (int i = 0; i < 4; i++) {
      af[i]  = *(const bf16x8*)(ard + i * 16 * 32);
      bfr[i] = *(const bf16x8*)(brd + i * 16 * 32);
    }
    if (!isv) {
#pragma unroll
      for (int mi = 0; mi < 4; mi++)
#pragma unroll
        for (int ni = 0; ni < 4; ni++)
          acc[mi][ni] = mfma16(af[mi], bfr[ni], acc[mi][ni]);
    } else {
#pragma unroll
      for (int ni = 0; ni < 4; ni++)
#pragma unroll
        for (int mi = 0; mi < 4; mi++)
          acc[ni][mi] = mfma16(bfr[ni], af[mi], acc[ni][mi]);
    }
  };

  stage(0, 0);
  __syncthreads();                       // buf0 ready (implicit vmcnt(0))
#pragma unroll 1
  for (int kt2 = 0; kt2 < 16; kt2++) {
    stage(1, 2 * kt2 + 1);               // prefetch in flight during compute
    compute(0);
    __syncthreads();                     // drains prefetch + buf0 reads
    if (kt2 < 15) stage(0, 2 * kt2 + 2);
    compute(1);
    __syncthreads();
  }

  const int chunk = (n0 >> 6) + wn;     // 0..47 = sel*16 + h
  const int sel = chunk >> 4, h = chunk & 15;
  if (!isv) {
    short* outp = (sel == 0) ? qo : ko;   // (B,H,T,Dh)
    // Q scale folds softmax 1/32 AND log2(e) (R20 exp2 fold)
    const float sc = (sel == 0) ? 0.045084441f : 1.0f;
#pragma unroll
    for (int mi = 0; mi < 4; mi++) {
#pragma unroll
      for (int r = 0; r < 4; r++) {
        int tg = m0 + wm * 64 + mi * 16 + quad * 4 + r;
        int b = tg >> 11, tl = tg & 2047;
        size_t rowb = ((size_t)(b * H_NUM + h) * T_SEQ + tl) * D_HEAD;
#pragma unroll
        for (int ni = 0; ni < 4; ni++)
          outp[rowb + ni * 16 + l15] = f2bf(acc[mi][ni][r] * sc);
      }
    }
  } else {
#pragma unroll
    for (int ni = 0; ni < 4; ni++) {
#pragma unroll
      for (int r = 0; r < 4; r++) {
        int d = ni * 16 + quad * 4 + r;
#pragma unroll
        for (int mi = 0; mi < 4; mi++) {
          int tg = m0 + wm * 64 + mi * 16 + l15;
          int b = tg >> 11, tl = tg & 2047;
          vto[((size_t)(b * H_NUM + h) * D_HEAD + d) * T_SEQ + tl] =
              f2bf(acc[ni][mi][r]);
        }
      }
    }
  }
}

// ---------------------------------------------------------------------------
// Kernel 3: flash attention partials, R22 LDS-shared K/V + R23 dbuf.
// grid 1280 x 256 (4 waves = 4 row-groups of one q-tile). hb = id&31 (XCD
// pin), p = id>>5 walks R13 order[]. Per block: one (qtb, 512-key chunk).
// K/V double-buffered: stage t+1 at iter top (full compute to land), ONE
// barrier per tile. XOR-swizzled via pre-swizzled global source. LDS 48KB.
__global__ __launch_bounds__(256) void attn_part_kernel(
    const short* __restrict__ q, const short* __restrict__ k,
    const short* __restrict__ vt, short* __restrict__ po,
    float* __restrict__ pl) {
  static const unsigned char order[NCHUNK] = {
      3, 4, 6, 8, 10, 11, 12, 13, 15, 16, 18, 19, 21, 22, 23, 24, 25, 26,
      28, 29, 30, 32, 33, 34, 36, 37, 38, 39,   // 8 iters
      2, 9, 20, 35,                             // 6 iters
      1, 7, 17, 31,                             // 4 iters
      0, 5, 14, 27};                            // 2 iters
  static const unsigned char qtb_of[NCHUNK] = {
      0, 1, 2, 3, 4, 4, 5, 5, 6, 6, 7, 7, 8, 8, 8, 9, 9, 9, 10, 10,
      10, 11, 11, 11, 12, 12, 12, 12, 13, 13, 13, 13, 14, 14, 14, 14,
      15, 15, 15, 15};
  static const unsigned char base16[16] = {0, 1, 2, 3, 4, 6, 8, 10,
                                           12, 15, 18, 21, 24, 28, 32, 36};
  const int id = blockIdx.x;
  const int hb = id & 31;          // b*16+h; XCD-pinned: id%8 == hb%8
  const int p  = id >> 5;          // 0..39, launch order = makespan order
  const int pblk = order[p];
  const int qtb = qtb_of[pblk];
  const int sbeg = (pblk - base16[qtb]) * 512;
  const int send = min(sbeg + 512, (qtb + 1) * 128);

  const size_t bh = (size_t)hb;
  const short* qp = q  + bh * T_SEQ * D_HEAD;
  const short* kp = k  + bh * T_SEQ * D_HEAD;
  const short* vp = vt + bh * D_HEAD * T_SEQ;   // (Dh, T)

  const int tid = threadIdx.x;
  const int w4 = tid >> 6;         // row-group 0..3 (one wave each)
  const int lane = tid & 63;
  const int l15 = lane & 15, quad = lane >> 4;
  const int swz8 = (l15 & 7) * 8;  // reader XOR (shorts)

  // LDS: K/V tiles double-buffered [64][64], P [4][32][64]; rows 64 shorts,
  // content XOR-swizzled by ((row&7)*8) shorts. Total 48KB.
  __shared__ __align__(16) short Ks[2][4096];
  __shared__ __align__(16) short Vs[2][4096];
  __shared__ __align__(16) short Ps[4][2048];
  short* pp = Ps[w4];

  const int q0w = qtb * 128 + w4 * 32;
  const int iters = (send - sbeg) >> 6;   // 2,4,6,8 — always even

  // ---- staging addresses (pre-swizzled global source, linear LDS dst) ----
  // wave w4 stages rows [w4*16, w4*16+16): instr i covers rows +i*8.
  const int srow = w4 * 16 + (lane >> 3);                  // + i*8
  const int scol = ((lane & 7) ^ (lane >> 3)) * 8;         // swizzled col
  const short* gK0 = kp + (size_t)(sbeg + srow) * 64 + scol;
  const short* gK1 = kp + (size_t)(sbeg + srow + 8) * 64 + scol;
  const short* gV0 = vp + (size_t)srow * 2048 + sbeg + scol;
  const short* gV1 = vp + (size_t)(srow + 8) * 2048 + sbeg + scol;
  const int lofs = w4 * 1024 + lane * 8;

  auto stageKV = [&](short* Kb, short* Vb, int toff) {   // toff = s0 - sbeg
    gload_lds16(gK0 + (size_t)toff * 64, Kb + lofs);
    gload_lds16(gK1 + (size_t)toff * 64, Kb + lofs + 512);
    gload_lds16(gV0 + toff, Vb + lofs);
    gload_lds16(gV1 + toff, Vb + lofs + 512);
  };

  // reader offsets (shorts): row*64 + (col ^ swz8)
  const int rbase = l15 * 64;
  const int koff0 = (quad * 8) ^ swz8;        // col block 0
  const int koff1 = (32 + quad * 8) ^ swz8;   // col block 1

  // Q fragments (global, once per block)
  bf16x8 qa[2][2];
#pragma unroll
  for (int h2 = 0; h2 < 2; h2++)
#pragma unroll
    for (int c2 = 0; c2 < 2; c2++)
      qa[h2][c2] = *(const bf16x8*)(qp + (size_t)(q0w + h2 * 16 + l15) * D_HEAD
                                    + c2 * 32 + quad * 8);

  f32x4 o[2][4];
#pragma unroll
  for (int h2 = 0; h2 < 2; h2++)
#pragma unroll
    for (int c = 0; c < 4; c++) o[h2][c] = f32x4{0, 0, 0, 0};
  float l_i[2] = { 0.f, 0.f };

  auto computeTile = [&](const short* Kb, const short* Vb, int s0) {
    // (1) S^T = K Q^T from LDS K tile
    f32x4 s[2][4];
    __builtin_amdgcn_s_setprio(1);
#pragma unroll
    for (int c = 0; c < 4; c++) {
      bf16x8 k0 = *(const bf16x8*)(Kb + c * 1024 + rbase + koff0);
      bf16x8 k1 = *(const bf16x8*)(Kb + c * 1024 + rbase + koff1);
#pragma unroll
      for (int h2 = 0; h2 < 2; h2++) {
        f32x4 z = { 0, 0, 0, 0 };
        z = mfma16(k0, qa[h2][0], z);
        z = mfma16(k1, qa[h2][1], z);
        s[h2][c] = z;
      }
    }
    __builtin_amdgcn_s_setprio(0);

    // (2) fixed-shift softmax: p = exp2(s) (s pre-scaled by log2e)
    const bool needMask = (s0 + 64 > q0w);   // wave-uniform
#pragma unroll
    for (int h2 = 0; h2 < 2; h2++) {
      const int qg = q0w + h2 * 16 + l15;
      if (needMask) {
#pragma unroll
        for (int c = 0; c < 4; c++)
#pragma unroll
          for (int r = 0; r < 4; r++)
            if (s0 + c * 16 + quad * 4 + r > qg) s[h2][c][r] = -1e30f;
      }
      float rs = 0.f;
#pragma unroll
      for (int c = 0; c < 4; c++) {
#pragma unroll
        for (int r = 0; r < 4; r++) {
          float p2 = exp2_hw(s[h2][c][r]);  // bare v_exp_f32; masked -> 0
          s[h2][c][r] = p2;
          rs += p2;
        }
      }
      l_i[h2] += rs;
      // (3) P pack (cvt_pk) -> swizzled P_lds row h2*16+l15
#pragma unroll
      for (int c = 0; c < 4; c++) {
        uint2 pw;
        pw.x = cvtpk_bf16(s[h2][c][0], s[h2][c][1]);
        pw.y = cvtpk_bf16(s[h2][c][2], s[h2][c][3]);
        *(uint2*)(pp + (h2 * 16 + l15) * 64 + ((c * 16 + quad * 4) ^ swz8)) = pw;
      }
    }
    asm volatile("" ::: "memory");   // wave-private LDS RAW (in-order DS)

    // (4) O^T += V^T P^T from LDS V tile
    __builtin_amdgcn_s_setprio(1);
#pragma unroll
    for (int kb2 = 0; kb2 < 2; kb2++) {
      const int ko = kb2 ? koff1 : koff0;
      bf16x8 pb0 = *(const bf16x8*)(pp + rbase + ko);
      bf16x8 pb1 = *(const bf16x8*)(pp + 1024 + rbase + ko);
#pragma unroll
      for (int c = 0; c < 4; c++) {
        bf16x8 va = *(const bf16x8*)(Vb + c * 1024 + rbase + ko);
        o[0][c] = mfma16(va, pb0, o[0][c]);
        o[1][c] = mfma16(va, pb1, o[1][c]);
      }
    }
    __builtin_amdgcn_s_setprio(0);
    asm volatile("" ::: "memory");   // WAR: next P writes after these reads
  };

  stageKV(Ks[0], Vs[0], 0);
  __syncthreads();                   // buf0 tile 0 ready (implicit vmcnt(0))
#pragma unroll 1
  for (int t = 0; t < iters; t += 2) {
    stageKV(Ks[1], Vs[1], (t + 1) * 64);   // in flight during compute(buf0)
    computeTile(Ks[0], Vs[0], sbeg + t * 64);
    __syncthreads();                       // buf1 ready; buf0 reads done
    if (t + 2 < iters) stageKV(Ks[0], Vs[0], (t + 2) * 64);
    computeTile(Ks[1], Vs[1], sbeg + (t + 1) * 64);
    __syncthreads();                       // buf0 ready; buf1 reads done
  }

  // epilogue: reduce l across quads, write partials (R13 po/pl layout).
  const size_t prow = (bh * NCHUNK + pblk) * 128;
#pragma unroll
  for (int h2 = 0; h2 < 2; h2++) {
    float lsum = l_i[h2];
    lsum += __shfl_xor(lsum, 16);
    lsum += __shfl_xor(lsum, 32);
    float inv = (lsum > 0.f) ? 1.0f / lsum : 0.f;
    int qlocal = w4 * 32 + h2 * 16 + l15;
    size_t rowoff = (prow + qlocal) * 64;
#pragma unroll
    for (int c = 0; c < 4; c++) {
      uint2 ow;
      ow.x = cvtpk_bf16(o[h2][c][0] * inv, o[h2][c][1] * inv);
      ow.y = cvtpk_bf16(o[h2][c][2] * inv, o[h2][c][3] * inv);
      *(uint2*)(&po[rowoff + c * 16 + quad * 4]) = ow;
    }
    if (quad == 0) pl[prow + qlocal] = lsum;
  }
}

// ---------------------------------------------------------------------------
// Kernel 3b: merge <=4 partials -> attnb (B,T,C) bf16. grid 2048 x 256.
// Fixed-shift partials: exact merge weights are the raw l's.
__global__ __launch_bounds__(256) void attn_merge_kernel(
    const short* __restrict__ po, const float* __restrict__ pl,
    short* __restrict__ attnb) {
  static const unsigned char base16[16] = {0, 1, 2, 3, 4, 6, 8, 10,
                                           12, 15, 18, 21, 24, 28, 32, 36};
  int id = blockIdx.x * 256 + threadIdx.x;   // 0..524287
  int dg = id & 7;
  int h  = (id >> 3) & 15;
  int t  = (id >> 7) & 2047;
  int b  = id >> 18;
  int qtb = t >> 7, ql = t & 127;
  int nch = (qtb >> 2) + 1;                  // ceil((qtb+1)/4)
  size_t bh = (size_t)(b * H_NUM + h);
  size_t r0 = (bh * NCHUNK + base16[qtb]) * 128 + ql;
  bf16x8 res;
  if (nch == 1) {
    res = *(const bf16x8*)(po + r0 * 64 + dg * 8);
  } else {
    float acc[8] = {0, 0, 0, 0, 0, 0, 0, 0};
    float lsum = 0.f;
    for (int c = 0; c < nch; c++) {
      size_t r = r0 + (size_t)c * 128;
      float lc = pl[r];
      lsum += lc;
      bf16x8 p = *(const bf16x8*)(po + r * 64 + dg * 8);
#pragma unroll
      for (int j = 0; j < 8; j++) acc[j] += lc * bf2f(p[j]);
    }
    float inv = 1.0f / lsum;
#pragma unroll
    for (int j = 0; j < 8; j++) res[j] = f2bf(acc[j] * inv);
  }
  *(bf16x8*)(&attnb[((size_t)(b * T_SEQ + t)) * C_DIM + h * D_HEAD + dg * 8]) = res;
}

// ---------------------------------------------------------------------------
// Kernel 4: output projection, R17 2-phase double-buffered. grid (32, 8).
__global__ __launch_bounds__(256) void proj_kernel(
    const short* __restrict__ a_in, const short* __restrict__ wpT,
    const float* __restrict__ bias, float* __restrict__ out) {
  const int m0 = blockIdx.x * 128;
  const int n0 = blockIdx.y * 128;
  const int tid = threadIdx.x, w = tid >> 6, lane = tid & 63;
  const int l15 = lane & 15, quad = lane >> 4;
  const int wm = w >> 1, wn = w & 1;

  __shared__ __align__(16) short As[2][128 * 32];
  __shared__ __align__(16) short Bs[2][128 * 32];

  const int srow = w * 32 + (lane >> 2);
  const int skof = (lane & 3) * 8;
  const short* ga0 = a_in + (size_t)(m0 + srow) * 1024 + skof;
  const short* ga1 = ga0 + 16 * 1024;
  const short* gb0 = wpT + (size_t)(n0 + srow) * 1024 + skof;
  const short* gb1 = gb0 + 16 * 1024;
  const int lof0 = (w * 32) * 32;
  const int lof1 = (w * 32 + 16) * 32;

  f32x4 acc[4][4];
#pragma unroll
  for (int i = 0; i < 4; i++)
#pragma unroll
    for (int j = 0; j < 4; j++) acc[i][j] = f32x4{0, 0, 0, 0};

  auto stage = [&](int bi, int kt) {
    const int k0 = kt * 32;
    gload_lds16(ga0 + k0, &As[bi][lof0]);
    gload_lds16(ga1 + k0, &As[bi][lof1]);
    gload_lds16(gb0 + k0, &Bs[bi][lof0]);
    gload_lds16(gb1 + k0, &Bs[bi][lof1]);
  };
  auto compute = [&](int bi) {
    const short* ard = &As[bi][(wm * 64 + l15) * 32 + quad * 8];
    const short* brd = &Bs[bi][(wn * 64 + l15) * 32 + quad * 8];
    bf16x8 af[4], bfr[4];
#pragma unroll
    for (int i = 0; i < 4; i++) {
      af[i]  = *(const bf16x8*)(ard + i * 16 * 32);
      bfr[i] = *(const bf16x8*)(brd + i * 16 * 32);
    }
#pragma unroll
    for (int mi = 0; mi < 4; mi++)
#pragma unroll
      for (int ni = 0; ni < 4; ni++)
        acc[mi][ni] = mfma16(af[mi], bfr[ni], acc[mi][ni]);
  };

  stage(0, 0);
  __syncthreads();
#pragma unroll 1
  for (int kt2 = 0; kt2 < 16; kt2++) {
    stage(1, 2 * kt2 + 1);
    compute(0);
    __syncthreads();
    if (kt2 < 15) stage(0, 2 * kt2 + 2);
    compute(1);
    __syncthreads();
  }

#pragma unroll
  for (int mi = 0; mi < 4; mi++) {
#pragma unroll
    for (int r = 0; r < 4; r++) {
      int mq = m0 + wm * 64 + mi * 16 + quad * 4 + r;
#pragma unroll
      for (int ni = 0; ni < 4; ni++) {
        int n = n0 + wn * 64 + ni * 16 + l15;
        out[(size_t)mq * C_DIM + n] = acc[mi][ni][r] + bias[n];
      }
    }
  }
}

// ---------------------------------------------------------------------------
extern "C" void kernel_launch(void* const* d_in, const int* in_sizes, int n_in,
                              void* d_out, int out_size, void* d_ws, size_t ws_size,
                              hipStream_t stream) {
  const float* x     = (const float*)d_in[0];
  const float* wq    = (const float*)d_in[1];
  const float* wk    = (const float*)d_in[2];
  const float* wv    = (const float*)d_in[3];
  const float* wproj = (const float*)d_in[4];
  const float* bias  = (const float*)d_in[5];

  short* ws = (short*)d_ws;
  // ws (16M shorts = 32 MB):
  short* wpT    = ws;                      // 1,048,576
  short* qb     = ws + 1048576;            // 4,194,304  (B,H,T,Dh), pre-scaled
  short* wt_qkv = ws + 9437184;            // 3,145,728  (dead after qkv)
  short* xb     = ws + 12582912;           // 4,194,304  (dead after qkv)
  // overlays (live only after qkv / attn_part complete):
  short* po     = ws + 5242880;            // 10,485,760 (40*32 x 128 x 64)
  float* pl     = (float*)(ws + 15728640); // 163,840 floats
  short* attnb  = ws + 1048576;            // 4,194,304  (overlays dead qb)
  // K and V^T in d_out (16 MB scratch) until proj overwrites it:
  short* kb     = (short*)d_out;           // 4,194,304  (B,H,T,Dh)
  short* vtb    = (short*)d_out + 4194304; // 4,194,304  (B,H,Dh,T)

  ingest_kernel<<<5120, 256, 0, stream>>>(x, wq, wk, wv, wproj, xb, wt_qkv, wpT);
  qkv_kernel<<<dim3(32, 24), 256, 0, stream>>>(xb, wt_qkv, qb, kb, vtb);
  attn_part_kernel<<<NCHUNK * 32, 256, 0, stream>>>(qb, kb, vtb, po, pl);
  attn_merge_kernel<<<2048, 256, 0, stream>>>(po, pl, attnb);
  proj_kernel<<<dim3(32, 8), 256, 0, stream>>>(attnb, wpT, bias, (float*)d_out);
}

// Round 13
// 190.902 us; speedup vs baseline: 1.0340x; 1.0340x over previous
//
#include <hip/hip_runtime.h>

// MultiHeadAttention: B=2, T=2048, C=1024, H=16, Dh=64, causal, scale = C^-0.5 = 1/32.
// FP32 I/O (proven R5). bf16 MFMA pipeline, fp32 accumulation.
//
//   1. ingest: R18 LDS-tiled transposes (proven).
//   2. qkv:    128x128 GEMM, R17 2-phase dbuf. Q scale = 1/32*log2e (R20).
//   3. attn_part: R22 LDS-shared K/V, single-buffer (PROVEN 196.4us total;
//      R23 dbuf was neutral — TLP at 4 blocks/CU already hid the staging
//      stall, and 48KB LDS cut a block. Reverted.)
//   4. attn_merge: R13 <=4-partial merge, weights = raw l (exact).
//   5. proj:   R25 64x128 tiles -> grid (64,8)=512 blocks = 2/CU (was
//      128x128, 256 blocks = 1/CU: zero TLP, barrier drains fully exposed,
//      ~30us for 8.6GF). Same R17 2-phase dbuf loop; 4 waves each own
//      64x32 out (acc[4][2]). LDS 24KB.
//
// ws layout (16M shorts = 32 MB):
//   wpT[0,1M) qb[1M,5.24M) wt[9.44M,12.58M) xb[12.58M,16.77M)
//   after qkv: po[5.24M,15.73M) = 40*32 x 128 x 64 bf16; pl[15.73M,+163840f)
//   attnb[1M,5.24M) overlays dead qb. K/V^T in d_out until proj.
//
// MFMA fragment layouts (HW-verified R6/R7):
//   A:   lane holds A[m=lane&15][k=quad*8+j], j=0..7   (quad = lane>>4)
//   B:   lane holds B[k=quad*8+j][n=lane&15]
//   C/D: lane holds D[m=quad*4+r][n=lane&15], r=0..3

typedef unsigned short u16;
typedef unsigned int u32;

using bf16x8 = __attribute__((ext_vector_type(8))) short;
using bf16x4 = __attribute__((ext_vector_type(4))) short;
using f32x4  = __attribute__((ext_vector_type(4))) float;

#define T_SEQ 2048
#define C_DIM 1024
#define H_NUM 16
#define D_HEAD 64
#define NCHUNK 40

static __device__ inline f32x4 mfma16(bf16x8 a, bf16x8 b, f32x4 c) {
  return __builtin_amdgcn_mfma_f32_16x16x32_bf16(a, b, c, 0, 0, 0);
}

static __device__ inline short f2bf(float f) {
  union { float f; u32 u; } v; v.f = f;
  u32 u = v.u;
  return (short)((u + 0x7FFFu + ((u >> 16) & 1u)) >> 16);
}

static __device__ inline float bf2f(short s) {
  union { u32 u; float f; } v; v.u = ((u32)(u16)s) << 16;
  return v.f;
}

// bare v_exp_f32: computes 2^x
static __device__ inline float exp2_hw(float x) {
  return __builtin_amdgcn_exp2f(x);
}

// pack 2 f32 -> 1 u32 of 2 bf16 (lo=a, hi=b), single HW instr
static __device__ inline u32 cvtpk_bf16(float a, float b) {
  u32 r;
  asm("v_cvt_pk_bf16_f32 %0, %1, %2" : "=v"(r) : "v"(a), "v"(b));
  return r;
}

// async global->LDS, 16B per lane; LDS dst = wave-uniform base + lane*16
static __device__ inline void gload_lds16(const short* g, short* l) {
  __builtin_amdgcn_global_load_lds(
      (const __attribute__((address_space(1))) unsigned int*)g,
      (__attribute__((address_space(3))) unsigned int*)l,
      16, 0, 0);
}

// ---------------------------------------------------------------------------
// Kernel 1: ingest, R18 tiled. grid 5120 x 256.
__global__ __launch_bounds__(256) void ingest_kernel(
    const float* __restrict__ x, const float* __restrict__ wq,
    const float* __restrict__ wk, const float* __restrict__ wv,
    const float* __restrict__ wproj,
    short* __restrict__ xb, short* __restrict__ wt, short* __restrict__ wpT) {
  const int bid = blockIdx.x, t = threadIdx.x;
  if (bid < 4096) {
    size_t i4 = ((size_t)bid * 256 + t) * 4;
    const float4 v = *(const float4*)(x + i4);
    bf16x4 o4;
    o4[0] = f2bf(v.x); o4[1] = f2bf(v.y); o4[2] = f2bf(v.z); o4[3] = f2bf(v.w);
    *(bf16x4*)(xb + i4) = o4;
    return;
  }
  __shared__ short lt[64][72];
  const int rl = t >> 2, q16 = (t & 3) * 16;
  if (bid < 4864) {
    const int wb = bid - 4096;
    const int h3 = wb >> 4, c0 = (wb & 15) * 64;
    const float* w = (h3 < 16) ? wq : (h3 < 32) ? wk : wv;
    const int h = h3 & 15;
    const float* rp = w + (size_t)h * 65536 + (size_t)(c0 + rl) * 64 + q16;
#pragma unroll
    for (int j = 0; j < 16; j++) lt[rl][q16 + j] = f2bf(rp[j]);
    __syncthreads();
    short* op = wt + (size_t)h3 * 65536 + (size_t)rl * 1024 + c0 + q16;
#pragma unroll
    for (int j = 0; j < 16; j++) op[j] = lt[q16 + j][rl];
  } else {
    const int wc = bid - 4864;
    const int k0 = (wc >> 4) * 64, n0 = (wc & 15) * 64;
    const float* rp = wproj + (size_t)(k0 + rl) * 1024 + n0 + q16;
#pragma unroll
    for (int j = 0; j < 16; j++) lt[rl][q16 + j] = f2bf(rp[j]);
    __syncthreads();
    short* op = wpT + (size_t)(n0 + rl) * 1024 + k0 + q16;
#pragma unroll
    for (int j = 0; j < 16; j++) op[j] = lt[q16 + j][rl];
  }
}

// ---------------------------------------------------------------------------
// Kernel 2: QKV GEMM, R17 2-phase double-buffered. grid (32, 24), 256 thr.
__global__ __launch_bounds__(256) void qkv_kernel(
    const short* __restrict__ x, const short* __restrict__ wt,
    short* __restrict__ qo, short* __restrict__ ko, short* __restrict__ vto) {
  const int m0 = blockIdx.x * 128;
  const int n0 = blockIdx.y * 128;
  const int tid = threadIdx.x, w = tid >> 6, lane = tid & 63;
  const int l15 = lane & 15, quad = lane >> 4;
  const int wm = w >> 1, wn = w & 1;

  __shared__ __align__(16) short As[2][128 * 32];
  __shared__ __align__(16) short Bs[2][128 * 32];

  const int srow = w * 32 + (lane >> 2);
  const int skof = (lane & 3) * 8;
  const short* ga0 = x  + (size_t)(m0 + srow) * 1024 + skof;
  const short* ga1 = ga0 + 16 * 1024;
  const short* gb0 = wt + (size_t)(n0 + srow) * 1024 + skof;
  const short* gb1 = gb0 + 16 * 1024;
  const int lof0 = (w * 32) * 32;
  const int lof1 = (w * 32 + 16) * 32;

  f32x4 acc[4][4];
#pragma unroll
  for (int i = 0; i < 4; i++)
#pragma unroll
    for (int j = 0; j < 4; j++) acc[i][j] = f32x4{0, 0, 0, 0};

  const bool isv = (n0 >= 2048);   // V column-blocks: operand-swap mode

  auto stage = [&](int bi, int kt) {
    const int k0 = kt * 32;
    gload_lds16(ga0 + k0, &As[bi][lof0]);
    gload_lds16(ga1 + k0, &As[bi][lof1]);
    gload_lds16(gb0 + k0, &Bs[bi][lof0]);
    gload_lds16(gb1 + k0, &Bs[bi][lof1]);
  };
  auto compute = [&](int bi) {
    const short* ard = &As[bi][(wm * 64 + l15) * 32 + quad * 8];
    const short* brd = &Bs[bi][(wn * 64 + l15) * 32 + quad * 8];
    bf16x8 af[4], bfr[4];
#pragma unroll
    for (int i = 0; i < 4; i++) {
      af[i]  = *(const bf16x8*)(ard + i * 16 * 32);
      bfr[i] = *(const bf16x8*)(brd + i * 16 * 32);
    }
    if (!isv) {
#pragma unroll
      for (int mi = 0; mi < 4; mi++)
#pragma unroll
        for (int ni = 0; ni < 4; ni++)
          acc[mi][ni] = mfma16(af[mi], bfr[ni], acc[mi][ni]);
    } else {
#pragma unroll
      for (int ni = 0; ni < 4; ni++)
#pragma unroll
        for (int mi = 0; mi < 4; mi++)
          acc[ni][mi] = mfma16(bfr[ni], af[mi], acc[ni][mi]);
    }
  };

  stage(0, 0);
  __syncthreads();                       // buf0 ready (implicit vmcnt(0))
#pragma unroll 1
  for (int kt2 = 0; kt2 < 16; kt2++) {
    stage(1, 2 * kt2 + 1);               // prefetch in flight during compute
    compute(0);
    __syncthreads();                     // drains prefetch + buf0 reads
    if (kt2 < 15) stage(0, 2 * kt2 + 2);
    compute(1);
    __syncthreads();
  }

  const int chunk = (n0 >> 6) + wn;     // 0..47 = sel*16 + h
  const int sel = chunk >> 4, h = chunk & 15;
  if (!isv) {
    short* outp = (sel == 0) ? qo : ko;   // (B,H,T,Dh)
    // Q scale folds softmax 1/32 AND log2(e) (R20 exp2 fold)
    const float sc = (sel == 0) ? 0.045084441f : 1.0f;
#pragma unroll
    for (int mi = 0; mi < 4; mi++) {
#pragma unroll
      for (int r = 0; r < 4; r++) {
        int tg = m0 + wm * 64 + mi * 16 + quad * 4 + r;
        int b = tg >> 11, tl = tg & 2047;
        size_t rowb = ((size_t)(b * H_NUM + h) * T_SEQ + tl) * D_HEAD;
#pragma unroll
        for (int ni = 0; ni < 4; ni++)
          outp[rowb + ni * 16 + l15] = f2bf(acc[mi][ni][r] * sc);
      }
    }
  } else {
#pragma unroll
    for (int ni = 0; ni < 4; ni++) {
#pragma unroll
      for (int r = 0; r < 4; r++) {
        int d = ni * 16 + quad * 4 + r;
#pragma unroll
        for (int mi = 0; mi < 4; mi++) {
          int tg = m0 + wm * 64 + mi * 16 + l15;
          int b = tg >> 11, tl = tg & 2047;
          vto[((size_t)(b * H_NUM + h) * D_HEAD + d) * T_SEQ + tl] =
              f2bf(acc[ni][mi][r]);
        }
      }
    }
  }
}

// ---------------------------------------------------------------------------
// Kernel 3: flash attention partials, R22 LDS-shared K/V (single-buffer,
// PROVEN). grid 1280 x 256 (4 waves = 4 row-groups of one q-tile).
// hb = id&31 (XCD pin), p = id>>5 walks R13 order[]. K/V staged to LDS once
// per iter (m97 2-barrier loop), XOR-swizzled via pre-swizzled global
// source; P_lds same swizzle. LDS = 32KB exact.
__global__ __launch_bounds__(256) void attn_part_kernel(
    const short* __restrict__ q, const short* __restrict__ k,
    const short* __restrict__ vt, short* __restrict__ po,
    float* __restrict__ pl) {
  static const unsigned char order[NCHUNK] = {
      3, 4, 6, 8, 10, 11, 12, 13, 15, 16, 18, 19, 21, 22, 23, 24, 25, 26,
      28, 29, 30, 32, 33, 34, 36, 37, 38, 39,   // 8 iters
      2, 9, 20, 35,                             // 6 iters
      1, 7, 17, 31,                             // 4 iters
      0, 5, 14, 27};                            // 2 iters
  static const unsigned char qtb_of[NCHUNK] = {
      0, 1, 2, 3, 4, 4, 5, 5, 6, 6, 7, 7, 8, 8, 8, 9, 9, 9, 10, 10,
      10, 11, 11, 11, 12, 12, 12, 12, 13, 13, 13, 13, 14, 14, 14, 14,
      15, 15, 15, 15};
  static const unsigned char base16[16] = {0, 1, 2, 3, 4, 6, 8, 10,
                                           12, 15, 18, 21, 24, 28, 32, 36};
  const int id = blockIdx.x;
  const int hb = id & 31;          // b*16+h; XCD-pinned: id%8 == hb%8
  const int p  = id >> 5;          // 0..39, launch order = makespan order
  const int pblk = order[p];
  const int qtb = qtb_of[pblk];
  const int sbeg = (pblk - base16[qtb]) * 512;
  const int send = min(sbeg + 512, (qtb + 1) * 128);

  const size_t bh = (size_t)hb;
  const short* qp = q  + bh * T_SEQ * D_HEAD;
  const short* kp = k  + bh * T_SEQ * D_HEAD;
  const short* vp = vt + bh * D_HEAD * T_SEQ;   // (Dh, T)

  const int tid = threadIdx.x;
  const int w4 = tid >> 6;         // row-group 0..3 (one wave each)
  const int lane = tid & 63;
  const int l15 = lane & 15, quad = lane >> 4;
  const int swz8 = (l15 & 7) * 8;  // reader XOR (shorts)

  // LDS: K tile [64 keys][64 Dh], V tile [64 Dh][64 keys], P [4][32][64];
  // all rows 64 shorts (128B), content XOR-swizzled by ((row&7)*8) shorts.
  __shared__ __align__(16) short Ks[4096];
  __shared__ __align__(16) short Vs[4096];
  __shared__ __align__(16) short Ps[4][2048];
  short* pp = Ps[w4];

  const int q0w = qtb * 128 + w4 * 32;
  // block-uniform loop end (w4=3's coverage bound); lower waves' extra
  // iters are fully masked -> exact zeros.
  const int s_hi = min(send, ((qtb * 128 + 96 + 95) >> 6) << 6);

  // ---- staging addresses (pre-swizzled global source, linear LDS dst) ----
  // wave w4 stages rows [w4*16, w4*16+16): instr i covers rows +i*8.
  const int srow = w4 * 16 + (lane >> 3);                  // + i*8
  const int scol = ((lane & 7) ^ (lane >> 3)) * 8;         // swizzled col
  const short* gK0 = kp + (size_t)(sbeg + srow) * 64 + scol;
  const short* gK1 = kp + (size_t)(sbeg + srow + 8) * 64 + scol;
  const short* gV0 = vp + (size_t)srow * 2048 + sbeg + scol;
  const short* gV1 = vp + (size_t)(srow + 8) * 2048 + sbeg + scol;
  short* lK0 = Ks + w4 * 1024 + lane * 8;
  short* lK1 = Ks + w4 * 1024 + 512 + lane * 8;
  short* lV0 = Vs + w4 * 1024 + lane * 8;
  short* lV1 = Vs + w4 * 1024 + 512 + lane * 8;

  auto stageKV = [&](int toff) {   // toff = s0 - sbeg
    gload_lds16(gK0 + (size_t)toff * 64, lK0);
    gload_lds16(gK1 + (size_t)toff * 64, lK1);
    gload_lds16(gV0 + toff, lV0);
    gload_lds16(gV1 + toff, lV1);
  };

  // reader offsets (shorts): row*64 + (col ^ swz8)
  const int rbase = l15 * 64;
  const int koff0 = (quad * 8) ^ swz8;        // col block 0 (half/kb2 = 0)
  const int koff1 = (32 + quad * 8) ^ swz8;   // col block 1

  // Q fragments (global, once per block)
  bf16x8 qa[2][2];
#pragma unroll
  for (int h2 = 0; h2 < 2; h2++)
#pragma unroll
    for (int c2 = 0; c2 < 2; c2++)
      qa[h2][c2] = *(const bf16x8*)(qp + (size_t)(q0w + h2 * 16 + l15) * D_HEAD
                                    + c2 * 32 + quad * 8);

  f32x4 o[2][4];
#pragma unroll
  for (int h2 = 0; h2 < 2; h2++)
#pragma unroll
    for (int c = 0; c < 4; c++) o[h2][c] = f32x4{0, 0, 0, 0};
  float l_i[2] = { 0.f, 0.f };

  stageKV(0);

#pragma unroll 1
  for (int s0 = sbeg; s0 < s_hi; s0 += 64) {
    __syncthreads();               // stage complete (implicit vmcnt(0) drain)

    // (1) S^T = K Q^T from LDS K tile
    f32x4 s[2][4];
    __builtin_amdgcn_s_setprio(1);
#pragma unroll
    for (int c = 0; c < 4; c++) {
      bf16x8 k0 = *(const bf16x8*)(Ks + c * 1024 + rbase + koff0);
      bf16x8 k1 = *(const bf16x8*)(Ks + c * 1024 + rbase + koff1);
#pragma unroll
      for (int h2 = 0; h2 < 2; h2++) {
        f32x4 z = { 0, 0, 0, 0 };
        z = mfma16(k0, qa[h2][0], z);
        z = mfma16(k1, qa[h2][1], z);
        s[h2][c] = z;
      }
    }
    __builtin_amdgcn_s_setprio(0);

    // (2) fixed-shift softmax: p = exp2(s) (s pre-scaled by log2e)
    const bool needMask = (s0 + 64 > q0w);   // wave-uniform
#pragma unroll
    for (int h2 = 0; h2 < 2; h2++) {
      const int qg = q0w + h2 * 16 + l15;
      if (needMask) {
#pragma unroll
        for (int c = 0; c < 4; c++)
#pragma unroll
          for (int r = 0; r < 4; r++)
            if (s0 + c * 16 + quad * 4 + r > qg) s[h2][c][r] = -1e30f;
      }
      float rs = 0.f;
#pragma unroll
      for (int c = 0; c < 4; c++) {
#pragma unroll
        for (int r = 0; r < 4; r++) {
          float p2 = exp2_hw(s[h2][c][r]);  // bare v_exp_f32; masked -> 0
          s[h2][c][r] = p2;
          rs += p2;
        }
      }
      l_i[h2] += rs;
      // (3) P pack (cvt_pk) -> swizzled P_lds row h2*16+l15
#pragma unroll
      for (int c = 0; c < 4; c++) {
        uint2 pw;
        pw.x = cvtpk_bf16(s[h2][c][0], s[h2][c][1]);
        pw.y = cvtpk_bf16(s[h2][c][2], s[h2][c][3]);
        *(uint2*)(pp + (h2 * 16 + l15) * 64 + ((c * 16 + quad * 4) ^ swz8)) = pw;
      }
    }
    asm volatile("" ::: "memory");   // wave-private LDS RAW (in-order DS)

    // (4) O^T += V^T P^T from LDS V tile
    __builtin_amdgcn_s_setprio(1);
#pragma unroll
    for (int kb2 = 0; kb2 < 2; kb2++) {
      const int ko = kb2 ? koff1 : koff0;
      bf16x8 pb0 = *(const bf16x8*)(pp + rbase + ko);
      bf16x8 pb1 = *(const bf16x8*)(pp + 1024 + rbase + ko);
#pragma unroll
      for (int c = 0; c < 4; c++) {
        bf16x8 va = *(const bf16x8*)(Vs + c * 1024 + rbase + ko);
        o[0][c] = mfma16(va, pb0, o[0][c]);
        o[1][c] = mfma16(va, pb1, o[1][c]);
      }
    }
    __builtin_amdgcn_s_setprio(0);

    __syncthreads();               // all LDS reads done before next stage
    if (s0 + 64 < s_hi) stageKV(s0 + 64 - sbeg);
  }

  // epilogue: reduce l across quads, write partials (R13 po/pl layout).
  const size_t prow = (bh * NCHUNK + pblk) * 128;
#pragma unroll
  for (int h2 = 0; h2 < 2; h2++) {
    float lsum = l_i[h2];
    lsum += __shfl_xor(lsum, 16);
    lsum += __shfl_xor(lsum, 32);
    float inv = (lsum > 0.f) ? 1.0f / lsum : 0.f;
    int qlocal = w4 * 32 + h2 * 16 + l15;
    size_t rowoff = (prow + qlocal) * 64;
#pragma unroll
    for (int c = 0; c < 4; c++) {
      uint2 ow;
      ow.x = cvtpk_bf16(o[h2][c][0] * inv, o[h2][c][1] * inv);
      ow.y = cvtpk_bf16(o[h2][c][2] * inv, o[h2][c][3] * inv);
      *(uint2*)(&po[rowoff + c * 16 + quad * 4]) = ow;
    }
    if (quad == 0) pl[prow + qlocal] = lsum;
  }
}

// ---------------------------------------------------------------------------
// Kernel 3b: merge <=4 partials -> attnb (B,T,C) bf16. grid 2048 x 256.
// Fixed-shift partials: exact merge weights are the raw l's.
__global__ __launch_bounds__(256) void attn_merge_kernel(
    const short* __restrict__ po, const float* __restrict__ pl,
    short* __restrict__ attnb) {
  static const unsigned char base16[16] = {0, 1, 2, 3, 4, 6, 8, 10,
                                           12, 15, 18, 21, 24, 28, 32, 36};
  int id = blockIdx.x * 256 + threadIdx.x;   // 0..524287
  int dg = id & 7;
  int h  = (id >> 3) & 15;
  int t  = (id >> 7) & 2047;
  int b  = id >> 18;
  int qtb = t >> 7, ql = t & 127;
  int nch = (qtb >> 2) + 1;                  // ceil((qtb+1)/4)
  size_t bh = (size_t)(b * H_NUM + h);
  size_t r0 = (bh * NCHUNK + base16[qtb]) * 128 + ql;
  bf16x8 res;
  if (nch == 1) {
    res = *(const bf16x8*)(po + r0 * 64 + dg * 8);
  } else {
    float acc[8] = {0, 0, 0, 0, 0, 0, 0, 0};
    float lsum = 0.f;
    for (int c = 0; c < nch; c++) {
      size_t r = r0 + (size_t)c * 128;
      float lc = pl[r];
      lsum += lc;
      bf16x8 p = *(const bf16x8*)(po + r * 64 + dg * 8);
#pragma unroll
      for (int j = 0; j < 8; j++) acc[j] += lc * bf2f(p[j]);
    }
    float inv = 1.0f / lsum;
#pragma unroll
    for (int j = 0; j < 8; j++) res[j] = f2bf(acc[j] * inv);
  }
  *(bf16x8*)(&attnb[((size_t)(b * T_SEQ + t)) * C_DIM + h * D_HEAD + dg * 8]) = res;
}

// ---------------------------------------------------------------------------
// Kernel 4: output projection, R25 64x128 tiles + R17 2-phase dbuf.
// grid (64, 8) = 512 blocks = 2/CU. 4 waves, each owns 64 rows x 32 cols
// (acc[4][2]); wave w = n-col group w*32. LDS 24KB.
__global__ __launch_bounds__(256) void proj_kernel(
    const short* __restrict__ a_in, const short* __restrict__ wpT,
    const float* __restrict__ bias, float* __restrict__ out) {
  const int m0 = blockIdx.x * 64;
  const int n0 = blockIdx.y * 128;
  const int tid = threadIdx.x, w = tid >> 6, lane = tid & 63;
  const int l15 = lane & 15, quad = lane >> 4;

  __shared__ __align__(16) short As[2][64 * 32];
  __shared__ __align__(16) short Bs[2][128 * 32];

  // A staging: wave w covers rows w*16+(lane>>2), 1 gload/thread
  const short* gaA = a_in + (size_t)(m0 + w * 16 + (lane >> 2)) * 1024
                     + (lane & 3) * 8;
  const int lofA = w * 16 * 32;            // + lane*8 shorts implicit
  // B staging: wave w covers rows w*32+(lane>>2) and +16 (2 gloads)
  const int srowB = w * 32 + (lane >> 2);
  const short* gb0 = wpT + (size_t)(n0 + srowB) * 1024 + (lane & 3) * 8;
  const short* gb1 = gb0 + 16 * 1024;
  const int lof0 = (w * 32) * 32;
  const int lof1 = (w * 32 + 16) * 32;

  f32x4 acc[4][2];
#pragma unroll
  for (int i = 0; i < 4; i++)
#pragma unroll
    for (int j = 0; j < 2; j++) acc[i][j] = f32x4{0, 0, 0, 0};

  auto stage = [&](int bi, int kt) {
    const int k0 = kt * 32;
    gload_lds16(gaA + k0, &As[bi][lofA]);
    gload_lds16(gb0 + k0, &Bs[bi][lof0]);
    gload_lds16(gb1 + k0, &Bs[bi][lof1]);
  };
  auto compute = [&](int bi) {
    const short* ard = &As[bi][l15 * 32 + quad * 8];
    const short* brd = &Bs[bi][(w * 32 + l15) * 32 + quad * 8];
    bf16x8 af[4], bfr[2];
#pragma unroll
    for (int i = 0; i < 4; i++)
      af[i] = *(const bf16x8*)(ard + i * 16 * 32);
#pragma unroll
    for (int j = 0; j < 2; j++)
      bfr[j] = *(const bf16x8*)(brd + j * 16 * 32);
#pragma unroll
    for (int mi = 0; mi < 4; mi++)
#pragma unroll
      for (int ni = 0; ni < 2; ni++)
        acc[mi][ni] = mfma16(af[mi], bfr[ni], acc[mi][ni]);
  };

  stage(0, 0);
  __syncthreads();
#pragma unroll 1
  for (int kt2 = 0; kt2 < 16; kt2++) {
    stage(1, 2 * kt2 + 1);
    compute(0);
    __syncthreads();
    if (kt2 < 15) stage(0, 2 * kt2 + 2);
    compute(1);
    __syncthreads();
  }

#pragma unroll
  for (int mi = 0; mi < 4; mi++) {
#pragma unroll
    for (int r = 0; r < 4; r++) {
      int mq = m0 + mi * 16 + quad * 4 + r;
#pragma unroll
      for (int ni = 0; ni < 2; ni++) {
        int n = n0 + w * 32 + ni * 16 + l15;
        out[(size_t)mq * C_DIM + n] = acc[mi][ni][r] + bias[n];
      }
    }
  }
}

// ---------------------------------------------------------------------------
extern "C" void kernel_launch(void* const* d_in, const int* in_sizes, int n_in,
                              void* d_out, int out_size, void* d_ws, size_t ws_size,
                              hipStream_t stream) {
  const float* x     = (const float*)d_in[0];
  const float* wq    = (const float*)d_in[1];
  const float* wk    = (const float*)d_in[2];
  const float* wv    = (const float*)d_in[3];
  const float* wproj = (const float*)d_in[4];
  const float* bias  = (const float*)d_in[5];

  short* ws = (short*)d_ws;
  // ws (16M shorts = 32 MB):
  short* wpT    = ws;                      // 1,048,576
  short* qb     = ws + 1048576;            // 4,194,304  (B,H,T,Dh), pre-scaled
  short* wt_qkv = ws + 9437184;            // 3,145,728  (dead after qkv)
  short* xb     = ws + 12582912;           // 4,194,304  (dead after qkv)
  // overlays (live only after qkv / attn_part complete):
  short* po     = ws + 5242880;            // 10,485,760 (40*32 x 128 x 64)
  float* pl     = (float*)(ws + 15728640); // 163,840 floats
  short* attnb  = ws + 1048576;            // 4,194,304  (overlays dead qb)
  // K and V^T in d_out (16 MB scratch) until proj overwrites it:
  short* kb     = (short*)d_out;           // 4,194,304  (B,H,T,Dh)
  short* vtb    = (short*)d_out + 4194304; // 4,194,304  (B,H,Dh,T)

  ingest_kernel<<<5120, 256, 0, stream>>>(x, wq, wk, wv, wproj, xb, wt_qkv, wpT);
  qkv_kernel<<<dim3(32, 24), 256, 0, stream>>>(xb, wt_qkv, qb, kb, vtb);
  attn_part_kernel<<<NCHUNK * 32, 256, 0, stream>>>(qb, kb, vtb, po, pl);
  attn_merge_kernel<<<2048, 256, 0, stream>>>(po, pl, attnb);
  proj_kernel<<<dim3(64, 8), 256, 0, stream>>>(attnb, wpT, bias, (float*)d_out);
}

// Round 14
// 190.215 us; speedup vs baseline: 1.0377x; 1.0036x over previous
//
#include <hip/hip_runtime.h>

// MultiHeadAttention: B=2, T=2048, C=1024, H=16, Dh=64, causal, scale = C^-0.5 = 1/32.
// FP32 I/O (proven R5). bf16 MFMA pipeline, fp32 accumulation.
//
//   1. ingest: R18 LDS-tiled transposes (proven).
//   2. qkv:    R26 64x128 tiles -> grid (64,24) = 1536 blocks = 6/CU (was
//      128x128 @ 3/CU: latency-bound, MfmaUtil 20%, ~74% of each K-step
//      exposed drain). Same R17 2-phase dbuf loop; 4 waves own 64x32 out;
//      flat acc[8] (normal mi*2+ni, V-swap ni*4+mi). LDS 24KB.
//      Q scale = 1/32*log2e (R20 exp2 fold).
//   3. attn_part: R22 LDS-shared K/V, single-buffer (proven; R23 dbuf
//      neutral and reverted).
//   4. attn_merge: R13 <=4-partial merge, weights = raw l (exact).
//   5. proj:   R25 64x128 tiles @ 2/CU (proven -6.5us).
//
// ws layout (16M shorts = 32 MB):
//   wpT[0,1M) qb[1M,5.24M) wt[9.44M,12.58M) xb[12.58M,16.77M)
//   after qkv: po[5.24M,15.73M) = 40*32 x 128 x 64 bf16; pl[15.73M,+163840f)
//   attnb[1M,5.24M) overlays dead qb. K/V^T in d_out until proj.
//
// MFMA fragment layouts (HW-verified R6/R7):
//   A:   lane holds A[m=lane&15][k=quad*8+j], j=0..7   (quad = lane>>4)
//   B:   lane holds B[k=quad*8+j][n=lane&15]
//   C/D: lane holds D[m=quad*4+r][n=lane&15], r=0..3

typedef unsigned short u16;
typedef unsigned int u32;

using bf16x8 = __attribute__((ext_vector_type(8))) short;
using bf16x4 = __attribute__((ext_vector_type(4))) short;
using f32x4  = __attribute__((ext_vector_type(4))) float;

#define T_SEQ 2048
#define C_DIM 1024
#define H_NUM 16
#define D_HEAD 64
#define NCHUNK 40

static __device__ inline f32x4 mfma16(bf16x8 a, bf16x8 b, f32x4 c) {
  return __builtin_amdgcn_mfma_f32_16x16x32_bf16(a, b, c, 0, 0, 0);
}

static __device__ inline short f2bf(float f) {
  union { float f; u32 u; } v; v.f = f;
  u32 u = v.u;
  return (short)((u + 0x7FFFu + ((u >> 16) & 1u)) >> 16);
}

static __device__ inline float bf2f(short s) {
  union { u32 u; float f; } v; v.u = ((u32)(u16)s) << 16;
  return v.f;
}

// bare v_exp_f32: computes 2^x
static __device__ inline float exp2_hw(float x) {
  return __builtin_amdgcn_exp2f(x);
}

// pack 2 f32 -> 1 u32 of 2 bf16 (lo=a, hi=b), single HW instr
static __device__ inline u32 cvtpk_bf16(float a, float b) {
  u32 r;
  asm("v_cvt_pk_bf16_f32 %0, %1, %2" : "=v"(r) : "v"(a), "v"(b));
  return r;
}

// async global->LDS, 16B per lane; LDS dst = wave-uniform base + lane*16
static __device__ inline void gload_lds16(const short* g, short* l) {
  __builtin_amdgcn_global_load_lds(
      (const __attribute__((address_space(1))) unsigned int*)g,
      (__attribute__((address_space(3))) unsigned int*)l,
      16, 0, 0);
}

// ---------------------------------------------------------------------------
// Kernel 1: ingest, R18 tiled. grid 5120 x 256.
__global__ __launch_bounds__(256) void ingest_kernel(
    const float* __restrict__ x, const float* __restrict__ wq,
    const float* __restrict__ wk, const float* __restrict__ wv,
    const float* __restrict__ wproj,
    short* __restrict__ xb, short* __restrict__ wt, short* __restrict__ wpT) {
  const int bid = blockIdx.x, t = threadIdx.x;
  if (bid < 4096) {
    size_t i4 = ((size_t)bid * 256 + t) * 4;
    const float4 v = *(const float4*)(x + i4);
    bf16x4 o4;
    o4[0] = f2bf(v.x); o4[1] = f2bf(v.y); o4[2] = f2bf(v.z); o4[3] = f2bf(v.w);
    *(bf16x4*)(xb + i4) = o4;
    return;
  }
  __shared__ short lt[64][72];
  const int rl = t >> 2, q16 = (t & 3) * 16;
  if (bid < 4864) {
    const int wb = bid - 4096;
    const int h3 = wb >> 4, c0 = (wb & 15) * 64;
    const float* w = (h3 < 16) ? wq : (h3 < 32) ? wk : wv;
    const int h = h3 & 15;
    const float* rp = w + (size_t)h * 65536 + (size_t)(c0 + rl) * 64 + q16;
#pragma unroll
    for (int j = 0; j < 16; j++) lt[rl][q16 + j] = f2bf(rp[j]);
    __syncthreads();
    short* op = wt + (size_t)h3 * 65536 + (size_t)rl * 1024 + c0 + q16;
#pragma unroll
    for (int j = 0; j < 16; j++) op[j] = lt[q16 + j][rl];
  } else {
    const int wc = bid - 4864;
    const int k0 = (wc >> 4) * 64, n0 = (wc & 15) * 64;
    const float* rp = wproj + (size_t)(k0 + rl) * 1024 + n0 + q16;
#pragma unroll
    for (int j = 0; j < 16; j++) lt[rl][q16 + j] = f2bf(rp[j]);
    __syncthreads();
    short* op = wpT + (size_t)(n0 + rl) * 1024 + k0 + q16;
#pragma unroll
    for (int j = 0; j < 16; j++) op[j] = lt[q16 + j][rl];
  }
}

// ---------------------------------------------------------------------------
// Kernel 2: QKV GEMM, R26 64x128 tiles + R17 2-phase dbuf. grid (64,24).
// 4 waves; wave w owns out cols w*32..w*32+31 of the 128-wide tile.
// chunk = (n0>>6) + (w>>1); half = w&1. LDS 24KB -> 6 blocks/CU.
__global__ __launch_bounds__(256) void qkv_kernel(
    const short* __restrict__ x, const short* __restrict__ wt,
    short* __restrict__ qo, short* __restrict__ ko, short* __restrict__ vto) {
  const int m0 = blockIdx.x * 64;
  const int n0 = blockIdx.y * 128;
  const int tid = threadIdx.x, w = tid >> 6, lane = tid & 63;
  const int l15 = lane & 15, quad = lane >> 4;

  __shared__ __align__(16) short As[2][64 * 32];
  __shared__ __align__(16) short Bs[2][128 * 32];

  // A staging: wave w covers rows w*16+(lane>>2), 1 gload/thread
  const short* gaA = x + (size_t)(m0 + w * 16 + (lane >> 2)) * 1024
                     + (lane & 3) * 8;
  const int lofA = w * 16 * 32;
  // B staging: wave w covers rows w*32+(lane>>2) and +16 (2 gloads)
  const int srowB = w * 32 + (lane >> 2);
  const short* gb0 = wt + (size_t)(n0 + srowB) * 1024 + (lane & 3) * 8;
  const short* gb1 = gb0 + 16 * 1024;
  const int lof0 = (w * 32) * 32;
  const int lof1 = (w * 32 + 16) * 32;

  f32x4 acc[8];
#pragma unroll
  for (int i = 0; i < 8; i++) acc[i] = f32x4{0, 0, 0, 0};

  const bool isv = (n0 >= 2048);   // V column-blocks: operand-swap mode

  auto stage = [&](int bi, int kt) {
    const int k0 = kt * 32;
    gload_lds16(gaA + k0, &As[bi][lofA]);
    gload_lds16(gb0 + k0, &Bs[bi][lof0]);
    gload_lds16(gb1 + k0, &Bs[bi][lof1]);
  };
  auto compute = [&](int bi) {
    const short* ard = &As[bi][l15 * 32 + quad * 8];
    const short* brd = &Bs[bi][(w * 32 + l15) * 32 + quad * 8];
    bf16x8 af[4], bfr[2];
#pragma unroll
    for (int i = 0; i < 4; i++)
      af[i] = *(const bf16x8*)(ard + i * 16 * 32);
#pragma unroll
    for (int j = 0; j < 2; j++)
      bfr[j] = *(const bf16x8*)(brd + j * 16 * 32);
    if (!isv) {
#pragma unroll
      for (int mi = 0; mi < 4; mi++)
#pragma unroll
        for (int ni = 0; ni < 2; ni++)
          acc[mi * 2 + ni] = mfma16(af[mi], bfr[ni], acc[mi * 2 + ni]);
    } else {
#pragma unroll
      for (int ni = 0; ni < 2; ni++)
#pragma unroll
        for (int mi = 0; mi < 4; mi++)
          acc[ni * 4 + mi] = mfma16(bfr[ni], af[mi], acc[ni * 4 + mi]);
    }
  };

  stage(0, 0);
  __syncthreads();                       // buf0 ready (implicit vmcnt(0))
#pragma unroll 1
  for (int kt2 = 0; kt2 < 16; kt2++) {
    stage(1, 2 * kt2 + 1);               // prefetch in flight during compute
    compute(0);
    __syncthreads();                     // drains prefetch + buf0 reads
    if (kt2 < 15) stage(0, 2 * kt2 + 2);
    compute(1);
    __syncthreads();
  }

  const int chunk = (n0 >> 6) + (w >> 1);   // 0..47 = sel*16 + h
  const int half = w & 1;                    // which 32-col half of chunk
  const int sel = chunk >> 4, h = chunk & 15;
  if (!isv) {
    short* outp = (sel == 0) ? qo : ko;   // (B,H,T,Dh)
    // Q scale folds softmax 1/32 AND log2(e) (R20 exp2 fold)
    const float sc = (sel == 0) ? 0.045084441f : 1.0f;
#pragma unroll
    for (int mi = 0; mi < 4; mi++) {
#pragma unroll
      for (int r = 0; r < 4; r++) {
        int tg = m0 + mi * 16 + quad * 4 + r;
        int b = tg >> 11, tl = tg & 2047;
        size_t rowb = ((size_t)(b * H_NUM + h) * T_SEQ + tl) * D_HEAD;
#pragma unroll
        for (int ni = 0; ni < 2; ni++)
          outp[rowb + half * 32 + ni * 16 + l15] =
              f2bf(acc[mi * 2 + ni][r] * sc);
      }
    }
  } else {
#pragma unroll
    for (int ni = 0; ni < 2; ni++) {
#pragma unroll
      for (int r = 0; r < 4; r++) {
        int d = half * 32 + ni * 16 + quad * 4 + r;
#pragma unroll
        for (int mi = 0; mi < 4; mi++) {
          int tg = m0 + mi * 16 + l15;
          int b = tg >> 11, tl = tg & 2047;
          vto[((size_t)(b * H_NUM + h) * D_HEAD + d) * T_SEQ + tl] =
              f2bf(acc[ni * 4 + mi][r]);
        }
      }
    }
  }
}

// ---------------------------------------------------------------------------
// Kernel 3: flash attention partials, R22 LDS-shared K/V (single-buffer,
// PROVEN). grid 1280 x 256 (4 waves = 4 row-groups of one q-tile).
// hb = id&31 (XCD pin), p = id>>5 walks R13 order[]. K/V staged to LDS once
// per iter (m97 2-barrier loop), XOR-swizzled via pre-swizzled global
// source; P_lds same swizzle. LDS = 32KB exact.
__global__ __launch_bounds__(256) void attn_part_kernel(
    const short* __restrict__ q, const short* __restrict__ k,
    const short* __restrict__ vt, short* __restrict__ po,
    float* __restrict__ pl) {
  static const unsigned char order[NCHUNK] = {
      3, 4, 6, 8, 10, 11, 12, 13, 15, 16, 18, 19, 21, 22, 23, 24, 25, 26,
      28, 29, 30, 32, 33, 34, 36, 37, 38, 39,   // 8 iters
      2, 9, 20, 35,                             // 6 iters
      1, 7, 17, 31,                             // 4 iters
      0, 5, 14, 27};                            // 2 iters
  static const unsigned char qtb_of[NCHUNK] = {
      0, 1, 2, 3, 4, 4, 5, 5, 6, 6, 7, 7, 8, 8, 8, 9, 9, 9, 10, 10,
      10, 11, 11, 11, 12, 12, 12, 12, 13, 13, 13, 13, 14, 14, 14, 14,
      15, 15, 15, 15};
  static const unsigned char base16[16] = {0, 1, 2, 3, 4, 6, 8, 10,
                                           12, 15, 18, 21, 24, 28, 32, 36};
  const int id = blockIdx.x;
  const int hb = id & 31;          // b*16+h; XCD-pinned: id%8 == hb%8
  const int p  = id >> 5;          // 0..39, launch order = makespan order
  const int pblk = order[p];
  const int qtb = qtb_of[pblk];
  const int sbeg = (pblk - base16[qtb]) * 512;
  const int send = min(sbeg + 512, (qtb + 1) * 128);

  const size_t bh = (size_t)hb;
  const short* qp = q  + bh * T_SEQ * D_HEAD;
  const short* kp = k  + bh * T_SEQ * D_HEAD;
  const short* vp = vt + bh * D_HEAD * T_SEQ;   // (Dh, T)

  const int tid = threadIdx.x;
  const int w4 = tid >> 6;         // row-group 0..3 (one wave each)
  const int lane = tid & 63;
  const int l15 = lane & 15, quad = lane >> 4;
  const int swz8 = (l15 & 7) * 8;  // reader XOR (shorts)

  // LDS: K tile [64 keys][64 Dh], V tile [64 Dh][64 keys], P [4][32][64];
  // all rows 64 shorts (128B), content XOR-swizzled by ((row&7)*8) shorts.
  __shared__ __align__(16) short Ks[4096];
  __shared__ __align__(16) short Vs[4096];
  __shared__ __align__(16) short Ps[4][2048];
  short* pp = Ps[w4];

  const int q0w = qtb * 128 + w4 * 32;
  // block-uniform loop end (w4=3's coverage bound); lower waves' extra
  // iters are fully masked -> exact zeros.
  const int s_hi = min(send, ((qtb * 128 + 96 + 95) >> 6) << 6);

  // ---- staging addresses (pre-swizzled global source, linear LDS dst) ----
  // wave w4 stages rows [w4*16, w4*16+16): instr i covers rows +i*8.
  const int srow = w4 * 16 + (lane >> 3);                  // + i*8
  const int scol = ((lane & 7) ^ (lane >> 3)) * 8;         // swizzled col
  const short* gK0 = kp + (size_t)(sbeg + srow) * 64 + scol;
  const short* gK1 = kp + (size_t)(sbeg + srow + 8) * 64 + scol;
  const short* gV0 = vp + (size_t)srow * 2048 + sbeg + scol;
  const short* gV1 = vp + (size_t)(srow + 8) * 2048 + sbeg + scol;
  short* lK0 = Ks + w4 * 1024 + lane * 8;
  short* lK1 = Ks + w4 * 1024 + 512 + lane * 8;
  short* lV0 = Vs + w4 * 1024 + lane * 8;
  short* lV1 = Vs + w4 * 1024 + 512 + lane * 8;

  auto stageKV = [&](int toff) {   // toff = s0 - sbeg
    gload_lds16(gK0 + (size_t)toff * 64, lK0);
    gload_lds16(gK1 + (size_t)toff * 64, lK1);
    gload_lds16(gV0 + toff, lV0);
    gload_lds16(gV1 + toff, lV1);
  };

  // reader offsets (shorts): row*64 + (col ^ swz8)
  const int rbase = l15 * 64;
  const int koff0 = (quad * 8) ^ swz8;        // col block 0 (half/kb2 = 0)
  const int koff1 = (32 + quad * 8) ^ swz8;   // col block 1

  // Q fragments (global, once per block)
  bf16x8 qa[2][2];
#pragma unroll
  for (int h2 = 0; h2 < 2; h2++)
#pragma unroll
    for (int c2 = 0; c2 < 2; c2++)
      qa[h2][c2] = *(const bf16x8*)(qp + (size_t)(q0w + h2 * 16 + l15) * D_HEAD
                                    + c2 * 32 + quad * 8);

  f32x4 o[2][4];
#pragma unroll
  for (int h2 = 0; h2 < 2; h2++)
#pragma unroll
    for (int c = 0; c < 4; c++) o[h2][c] = f32x4{0, 0, 0, 0};
  float l_i[2] = { 0.f, 0.f };

  stageKV(0);

#pragma unroll 1
  for (int s0 = sbeg; s0 < s_hi; s0 += 64) {
    __syncthreads();               // stage complete (implicit vmcnt(0) drain)

    // (1) S^T = K Q^T from LDS K tile
    f32x4 s[2][4];
    __builtin_amdgcn_s_setprio(1);
#pragma unroll
    for (int c = 0; c < 4; c++) {
      bf16x8 k0 = *(const bf16x8*)(Ks + c * 1024 + rbase + koff0);
      bf16x8 k1 = *(const bf16x8*)(Ks + c * 1024 + rbase + koff1);
#pragma unroll
      for (int h2 = 0; h2 < 2; h2++) {
        f32x4 z = { 0, 0, 0, 0 };
        z = mfma16(k0, qa[h2][0], z);
        z = mfma16(k1, qa[h2][1], z);
        s[h2][c] = z;
      }
    }
    __builtin_amdgcn_s_setprio(0);

    // (2) fixed-shift softmax: p = exp2(s) (s pre-scaled by log2e)
    const bool needMask = (s0 + 64 > q0w);   // wave-uniform
#pragma unroll
    for (int h2 = 0; h2 < 2; h2++) {
      const int qg = q0w + h2 * 16 + l15;
      if (needMask) {
#pragma unroll
        for (int c = 0; c < 4; c++)
#pragma unroll
          for (int r = 0; r < 4; r++)
            if (s0 + c * 16 + quad * 4 + r > qg) s[h2][c][r] = -1e30f;
      }
      float rs = 0.f;
#pragma unroll
      for (int c = 0; c < 4; c++) {
#pragma unroll
        for (int r = 0; r < 4; r++) {
          float p2 = exp2_hw(s[h2][c][r]);  // bare v_exp_f32; masked -> 0
          s[h2][c][r] = p2;
          rs += p2;
        }
      }
      l_i[h2] += rs;
      // (3) P pack (cvt_pk) -> swizzled P_lds row h2*16+l15
#pragma unroll
      for (int c = 0; c < 4; c++) {
        uint2 pw;
        pw.x = cvtpk_bf16(s[h2][c][0], s[h2][c][1]);
        pw.y = cvtpk_bf16(s[h2][c][2], s[h2][c][3]);
        *(uint2*)(pp + (h2 * 16 + l15) * 64 + ((c * 16 + quad * 4) ^ swz8)) = pw;
      }
    }
    asm volatile("" ::: "memory");   // wave-private LDS RAW (in-order DS)

    // (4) O^T += V^T P^T from LDS V tile
    __builtin_amdgcn_s_setprio(1);
#pragma unroll
    for (int kb2 = 0; kb2 < 2; kb2++) {
      const int ko = kb2 ? koff1 : koff0;
      bf16x8 pb0 = *(const bf16x8*)(pp + rbase + ko);
      bf16x8 pb1 = *(const bf16x8*)(pp + 1024 + rbase + ko);
#pragma unroll
      for (int c = 0; c < 4; c++) {
        bf16x8 va = *(const bf16x8*)(Vs + c * 1024 + rbase + ko);
        o[0][c] = mfma16(va, pb0, o[0][c]);
        o[1][c] = mfma16(va, pb1, o[1][c]);
      }
    }
    __builtin_amdgcn_s_setprio(0);

    __syncthreads();               // all LDS reads done before next stage
    if (s0 + 64 < s_hi) stageKV(s0 + 64 - sbeg);
  }

  // epilogue: reduce l across quads, write partials (R13 po/pl layout).
  const size_t prow = (bh * NCHUNK + pblk) * 128;
#pragma unroll
  for (int h2 = 0; h2 < 2; h2++) {
    float lsum = l_i[h2];
    lsum += __shfl_xor(lsum, 16);
    lsum += __shfl_xor(lsum, 32);
    float inv = (lsum > 0.f) ? 1.0f / lsum : 0.f;
    int qlocal = w4 * 32 + h2 * 16 + l15;
    size_t rowoff = (prow + qlocal) * 64;
#pragma unroll
    for (int c = 0; c < 4; c++) {
      uint2 ow;
      ow.x = cvtpk_bf16(o[h2][c][0] * inv, o[h2][c][1] * inv);
      ow.y = cvtpk_bf16(o[h2][c][2] * inv, o[h2][c][3] * inv);
      *(uint2*)(&po[rowoff + c * 16 + quad * 4]) = ow;
    }
    if (quad == 0) pl[prow + qlocal] = lsum;
  }
}

// ---------------------------------------------------------------------------
// Kernel 3b: merge <=4 partials -> attnb (B,T,C) bf16. grid 2048 x 256.
// Fixed-shift partials: exact merge weights are the raw l's.
__global__ __launch_bounds__(256) void attn_merge_kernel(
    const short* __restrict__ po, const float* __restrict__ pl,
    short* __restrict__ attnb) {
  static const unsigned char base16[16] = {0, 1, 2, 3, 4, 6, 8, 10,
                                           12, 15, 18, 21, 24, 28, 32, 36};
  int id = blockIdx.x * 256 + threadIdx.x;   // 0..524287
  int dg = id & 7;
  int h  = (id >> 3) & 15;
  int t  = (id >> 7) & 2047;
  int b  = id >> 18;
  int qtb = t >> 7, ql = t & 127;
  int nch = (qtb >> 2) + 1;                  // ceil((qtb+1)/4)
  size_t bh = (size_t)(b * H_NUM + h);
  size_t r0 = (bh * NCHUNK + base16[qtb]) * 128 + ql;
  bf16x8 res;
  if (nch == 1) {
    res = *(const bf16x8*)(po + r0 * 64 + dg * 8);
  } else {
    float acc[8] = {0, 0, 0, 0, 0, 0, 0, 0};
    float lsum = 0.f;
    for (int c = 0; c < nch; c++) {
      size_t r = r0 + (size_t)c * 128;
      float lc = pl[r];
      lsum += lc;
      bf16x8 p = *(const bf16x8*)(po + r * 64 + dg * 8);
#pragma unroll
      for (int j = 0; j < 8; j++) acc[j] += lc * bf2f(p[j]);
    }
    float inv = 1.0f / lsum;
#pragma unroll
    for (int j = 0; j < 8; j++) res[j] = f2bf(acc[j] * inv);
  }
  *(bf16x8*)(&attnb[((size_t)(b * T_SEQ + t)) * C_DIM + h * D_HEAD + dg * 8]) = res;
}

// ---------------------------------------------------------------------------
// Kernel 4: output projection, R25 64x128 tiles + R17 2-phase dbuf.
// grid (64, 8) = 512 blocks = 2/CU. 4 waves, each owns 64 rows x 32 cols
// (acc[4][2]); wave w = n-col group w*32. LDS 24KB.
__global__ __launch_bounds__(256) void proj_kernel(
    const short* __restrict__ a_in, const short* __restrict__ wpT,
    const float* __restrict__ bias, float* __restrict__ out) {
  const int m0 = blockIdx.x * 64;
  const int n0 = blockIdx.y * 128;
  const int tid = threadIdx.x, w = tid >> 6, lane = tid & 63;
  const int l15 = lane & 15, quad = lane >> 4;

  __shared__ __align__(16) short As[2][64 * 32];
  __shared__ __align__(16) short Bs[2][128 * 32];

  // A staging: wave w covers rows w*16+(lane>>2), 1 gload/thread
  const short* gaA = a_in + (size_t)(m0 + w * 16 + (lane >> 2)) * 1024
                     + (lane & 3) * 8;
  const int lofA = w * 16 * 32;            // + lane*8 shorts implicit
  // B staging: wave w covers rows w*32+(lane>>2) and +16 (2 gloads)
  const int srowB = w * 32 + (lane >> 2);
  const short* gb0 = wpT + (size_t)(n0 + srowB) * 1024 + (lane & 3) * 8;
  const short* gb1 = gb0 + 16 * 1024;
  const int lof0 = (w * 32) * 32;
  const int lof1 = (w * 32 + 16) * 32;

  f32x4 acc[4][2];
#pragma unroll
  for (int i = 0; i < 4; i++)
#pragma unroll
    for (int j = 0; j < 2; j++) acc[i][j] = f32x4{0, 0, 0, 0};

  auto stage = [&](int bi, int kt) {
    const int k0 = kt * 32;
    gload_lds16(gaA + k0, &As[bi][lofA]);
    gload_lds16(gb0 + k0, &Bs[bi][lof0]);
    gload_lds16(gb1 + k0, &Bs[bi][lof1]);
  };
  auto compute = [&](int bi) {
    const short* ard = &As[bi][l15 * 32 + quad * 8];
    const short* brd = &Bs[bi][(w * 32 + l15) * 32 + quad * 8];
    bf16x8 af[4], bfr[2];
#pragma unroll
    for (int i = 0; i < 4; i++)
      af[i] = *(const bf16x8*)(ard + i * 16 * 32);
#pragma unroll
    for (int j = 0; j < 2; j++)
      bfr[j] = *(const bf16x8*)(brd + j * 16 * 32);
#pragma unroll
    for (int mi = 0; mi < 4; mi++)
#pragma unroll
      for (int ni = 0; ni < 2; ni++)
        acc[mi][ni] = mfma16(af[mi], bfr[ni], acc[mi][ni]);
  };

  stage(0, 0);
  __syncthreads();
#pragma unroll 1
  for (int kt2 = 0; kt2 < 16; kt2++) {
    stage(1, 2 * kt2 + 1);
    compute(0);
    __syncthreads();
    if (kt2 < 15) stage(0, 2 * kt2 + 2);
    compute(1);
    __syncthreads();
  }

#pragma unroll
  for (int mi = 0; mi < 4; mi++) {
#pragma unroll
    for (int r = 0; r < 4; r++) {
      int mq = m0 + mi * 16 + quad * 4 + r;
#pragma unroll
      for (int ni = 0; ni < 2; ni++) {
        int n = n0 + w * 32 + ni * 16 + l15;
        out[(size_t)mq * C_DIM + n] = acc[mi][ni][r] + bias[n];
      }
    }
  }
}

// ---------------------------------------------------------------------------
extern "C" void kernel_launch(void* const* d_in, const int* in_sizes, int n_in,
                              void* d_out, int out_size, void* d_ws, size_t ws_size,
                              hipStream_t stream) {
  const float* x     = (const float*)d_in[0];
  const float* wq    = (const float*)d_in[1];
  const float* wk    = (const float*)d_in[2];
  const float* wv    = (const float*)d_in[3];
  const float* wproj = (const float*)d_in[4];
  const float* bias  = (const float*)d_in[5];

  short* ws = (short*)d_ws;
  // ws (16M shorts = 32 MB):
  short* wpT    = ws;                      // 1,048,576
  short* qb     = ws + 1048576;            // 4,194,304  (B,H,T,Dh), pre-scaled
  short* wt_qkv = ws + 9437184;            // 3,145,728  (dead after qkv)
  short* xb     = ws + 12582912;           // 4,194,304  (dead after qkv)
  // overlays (live only after qkv / attn_part complete):
  short* po     = ws + 5242880;            // 10,485,760 (40*32 x 128 x 64)
  float* pl     = (float*)(ws + 15728640); // 163,840 floats
  short* attnb  = ws + 1048576;            // 4,194,304  (overlays dead qb)
  // K and V^T in d_out (16 MB scratch) until proj overwrites it:
  short* kb     = (short*)d_out;           // 4,194,304  (B,H,T,Dh)
  short* vtb    = (short*)d_out + 4194304; // 4,194,304  (B,H,Dh,T)

  ingest_kernel<<<5120, 256, 0, stream>>>(x, wq, wk, wv, wproj, xb, wt_qkv, wpT);
  qkv_kernel<<<dim3(64, 24), 256, 0, stream>>>(xb, wt_qkv, qb, kb, vtb);
  attn_part_kernel<<<NCHUNK * 32, 256, 0, stream>>>(qb, kb, vtb, po, pl);
  attn_merge_kernel<<<2048, 256, 0, stream>>>(po, pl, attnb);
  proj_kernel<<<dim3(64, 8), 256, 0, stream>>>(attnb, wpT, bias, (float*)d_out);
}